// Round 1
// baseline (444.596 us; speedup 1.0000x reference)
//
#include <hip/hip_runtime.h>

typedef __attribute__((ext_vector_type(4))) float f4;
typedef __attribute__((ext_vector_type(2))) float f2;
typedef __attribute__((ext_vector_type(8))) short s8;   // 8 bf16 (4 VGPRs) MFMA frag

#define EPS 1e-5f

// ---- bit-exact RNE converters (kept for prep kernels) ----
__device__ __forceinline__ unsigned short f2bf(float f) {
    union { float f; unsigned u; } v; v.f = f;
    unsigned u = v.u;
    return (unsigned short)((u + 0x7fffu + ((u >> 16) & 1u)) >> 16);   // RNE
}
__device__ __forceinline__ unsigned pack2(float a, float b) {
    return (unsigned)f2bf(a) | ((unsigned)f2bf(b) << 16);
}

// ---- single-instruction packed converters (main kernel) ----
__device__ __forceinline__ unsigned cvt_pk2(float a, float b) {
    unsigned r;
    asm("v_cvt_pk_bf16_f32 %0, %1, %2" : "=v"(r) : "v"(a), "v"(b));
    return r;
}
__device__ __forceinline__ unsigned short cvt1(float a) {
    return (unsigned short)cvt_pk2(a, a);
}
__device__ __forceinline__ s8 pack8(f4 a, f4 b) {
    union { s8 v; unsigned u[4]; } r;
    r.u[0] = cvt_pk2(a[0], a[1]); r.u[1] = cvt_pk2(a[2], a[3]);
    r.u[2] = cvt_pk2(b[0], b[1]); r.u[3] = cvt_pk2(b[2], b[3]);
    return r.v;
}

// =================== prep1 (merged): weight frag-linear bf16 + A/cvec ===================
// FL layout: FL[((ksg*16 + ct)*64 + lane)*8 + j] = W[ct*16 + (lane&15)][ksg*32 + (lane>>4)*8 + j]
__global__ __launch_bounds__(256) void k_prep1(const float* __restrict__ text_w,
                                               const float* __restrict__ bio_w,
                                               const float* __restrict__ out_w,
                                               const float* __restrict__ in_proj_w,
                                               const float* __restrict__ in_proj_b,
                                               const float* __restrict__ out_b,
                                               unsigned short* __restrict__ twFL,
                                               unsigned short* __restrict__ bwFL,
                                               float* __restrict__ A,
                                               float* __restrict__ cvec) {
    int b = blockIdx.x, t = threadIdx.x;
    if (b < 96) {                       // text_w [256][768] -> 24 ksteps x 16 ct
        int idx = b * 256 + t;
        int ksg = idx >> 10;
        int rem = idx & 1023;
        int ct = rem >> 6, lane = rem & 63;
        int n  = ct * 16 + (lane & 15);
        int k0 = ksg * 32 + ((lane >> 4) << 3);
        const float* src = &text_w[n * 768 + k0];
        f4 a = *(const f4*)src, c = *(const f4*)(src + 4);
        unsigned* dst = (unsigned*)&twFL[idx * 8];
        dst[0] = pack2(a[0], a[1]); dst[1] = pack2(a[2], a[3]);
        dst[2] = pack2(c[0], c[1]); dst[3] = pack2(c[2], c[3]);
    } else if (b < 100) {               // bio_w [256][32] -> 1 kstep x 16 ct
        int idx = (b - 96) * 256 + t;
        int ct = idx >> 6, lane = idx & 63;
        int n  = ct * 16 + (lane & 15);
        int k0 = (lane >> 4) << 3;
        const float* src = &bio_w[n * 32 + k0];
        f4 a = *(const f4*)src, c = *(const f4*)(src + 4);
        unsigned* dst = (unsigned*)&bwFL[idx * 8];
        dst[0] = pack2(a[0], a[1]); dst[1] = pack2(a[2], a[3]);
        dst[2] = pack2(c[0], c[1]); dst[3] = pack2(c[2], c[3]);
    } else {                            // A = out_w @ Wv, cvec = out_w @ bv + out_b
        __shared__ float srow[256];
        __shared__ float red[256];
        int i = b - 100, j = t;
        srow[j] = out_w[i * 256 + j];
        __syncthreads();
        float acc = 0.f;
#pragma unroll 16
        for (int k = 0; k < 256; k++)
            acc = fmaf(srow[k], in_proj_w[(512 + k) * 256 + j], acc);
        A[i * 256 + j] = acc;
        red[j] = srow[j] * in_proj_b[512 + j];
        __syncthreads();
        for (int s = 128; s > 0; s >>= 1) {
            if (j < s) red[j] += red[j + s];
            __syncthreads();
        }
        if (j == 0) cvec[i] = red[0] + out_b[i];
    }
}

// =================== prep2: PQ weights (frag-linear bf16, LN-gain folded) + dvec ===================
__global__ __launch_bounds__(256) void k_prep_PQ(const float* __restrict__ cls1_w,
                                                 const float* __restrict__ cls1_b,
                                                 const float* __restrict__ A,
                                                 const float* __restrict__ cvec,
                                                 const float* __restrict__ ln_text_g,
                                                 const float* __restrict__ ln_text_b,
                                                 const float* __restrict__ ln_bio_g,
                                                 const float* __restrict__ ln_bio_b,
                                                 unsigned short* __restrict__ pqFL,
                                                 float* __restrict__ dvec) {
    __shared__ float w1[256], w2[256], red[256];
    int i = blockIdx.x, j = threadIdx.x;
    w1[j] = cls1_w[i * 512 + j];
    w2[j] = cls1_w[i * 512 + 256 + j];
    __syncthreads();
    float rp = 0.f, rq = 0.f;
#pragma unroll 8
    for (int k = 0; k < 256; k++) {
        float a = A[k * 256 + j];
        rp = fmaf(w1[k], a, rp);
        rq = fmaf(w2[k], a, rq);
    }
    int ct   = i >> 4;
    int lane = (i & 15) | (((j >> 3) & 3) << 4);
    int jj   = j & 7;
    int ks1  = j >> 5;
    pqFL[(((ks1     ) * 16 + ct) * 64 + lane) * 8 + jj] = f2bf(rp * ln_text_g[j]);
    pqFL[(((ks1 + 8 ) * 16 + ct) * 64 + lane) * 8 + jj] = f2bf(rq * ln_bio_g[j]);
    red[j] = rp * ln_text_b[j] + rq * ln_bio_b[j] + (w1[j] + w2[j]) * cvec[j];
    __syncthreads();
    for (int s = 128; s > 0; s >>= 1) {
        if (j < s) red[j] += red[j + s];
        __syncthreads();
    }
    if (j == 0) dvec[i] = red[0] + cls1_b[i];
}

// =================== main fused MFMA kernel ===================
// 64 rows/block, 512 threads = 8 waves: wave = (cs = w&3 col-slice of 64, rh = w>>2 row-half of 32).
// Stage B now loads text A-fragments DIRECTLY from global (16B/lane, full 64B lines),
// converting f32->bf16 in registers via v_cvt_pk_bf16_f32: no LDS staging, no chunk
// barriers, ~36 fewer live VGPRs (spill headroom), stage-B k-loop freely pipelined.
// s_red relayout: [row][cs][2] (48B row stride) -> b64 writes + 2x b128 broadcast reads.
__global__ __launch_bounds__(512, 4) void k_main(
    const float* __restrict__ bio, const float* __restrict__ text,
    const float* __restrict__ bio_b, const float* __restrict__ text_b,
    const float* __restrict__ cls_ln_g, const float* __restrict__ cls_ln_b,
    const float* __restrict__ cls2_w, const float* __restrict__ cls2_b,
    const unsigned short* __restrict__ twFL, const unsigned short* __restrict__ bwFL,
    const unsigned short* __restrict__ pqFL, const float* __restrict__ dvec,
    float* __restrict__ out)
{
    // row stride 520 u16 = 1040 B = 65*16: 16B-aligned rows, stride ≡ 4 banks → 2-way max on frag reads
    __shared__ __align__(16) unsigned short s_n[64][520];  // 65 KB; [row][k] n_t 0..255 | n_b 256..511
    __shared__ __align__(16) float s_red[64][6][2];        // 3 KB; [row][cs(0..3)+pad][{a,b}], 48B stride

    const int tid  = threadIdx.x;
    const int wv   = tid >> 6;
    const int cs   = wv & 3;          // col slice: cols [cs*64, cs*64+64)
    const int rh   = wv >> 2;         // row half: rows [rh*32, rh*32+32)
    const int lane = tid & 63;
    const int q    = lane >> 4;
    const int lr   = lane & 15;
    const int R0   = blockIdx.x * 64;

    f4 acc[2][4];
    float s1[2][4], s2[2][4], m_[2][4], iv_[2][4];

    // ---------------- stage A: x_b = bio @ bio_w.T + bio_b ; n_b ----------------
    f4 bioA[2], bioB[2];
#pragma unroll
    for (int rt = 0; rt < 2; rt++) {
        const float* p = &bio[(size_t)(R0 + rh * 32 + rt * 16 + lr) * 32 + q * 8];
        bioA[rt] = *(const f4*)p;
        bioB[rt] = *(const f4*)(p + 4);
    }
    s8 bfrb[4];
#pragma unroll
    for (int c = 0; c < 4; c++)
        bfrb[c] = *(const s8*)&bwFL[((cs * 4 + c) * 64 + lane) * 8];

#pragma unroll
    for (int rt = 0; rt < 2; rt++)
#pragma unroll
        for (int c = 0; c < 4; c++) acc[rt][c] = (f4){0.f, 0.f, 0.f, 0.f};
#pragma unroll
    for (int rt = 0; rt < 2; rt++) {
        s8 af = pack8(bioA[rt], bioB[rt]);
#pragma unroll
        for (int c = 0; c < 4; c++)
            acc[rt][c] = __builtin_amdgcn_mfma_f32_16x16x32_bf16(af, bfrb[c], acc[rt][c], 0, 0, 0);
    }
#pragma unroll
    for (int rt = 0; rt < 2; rt++)
#pragma unroll
        for (int r = 0; r < 4; r++) { s1[rt][r] = 0.f; s2[rt][r] = 0.f; }
#pragma unroll
    for (int rt = 0; rt < 2; rt++)
#pragma unroll
        for (int c = 0; c < 4; c++) {
            float bb = bio_b[cs * 64 + c * 16 + lr];
#pragma unroll
            for (int r = 0; r < 4; r++) {
                float x = acc[rt][c][r] + bb;
                acc[rt][c][r] = x;
                s1[rt][r] += x; s2[rt][r] += x * x;
            }
        }
#pragma unroll
    for (int off = 1; off < 16; off <<= 1)
#pragma unroll
        for (int rt = 0; rt < 2; rt++)
#pragma unroll
            for (int r = 0; r < 4; r++) {
                s1[rt][r] += __shfl_xor(s1[rt][r], off, 64);
                s2[rt][r] += __shfl_xor(s2[rt][r], off, 64);
            }
    if (lr == 0)
#pragma unroll
        for (int rt = 0; rt < 2; rt++)
#pragma unroll
            for (int r = 0; r < 4; r++) {
                int row = rh * 32 + rt * 16 + q * 4 + r;
                f2 v; v[0] = s1[rt][r]; v[1] = s2[rt][r];
                *(f2*)&s_red[row][cs][0] = v;
            }
    __syncthreads();
#pragma unroll
    for (int rt = 0; rt < 2; rt++)
#pragma unroll
        for (int r = 0; r < 4; r++) {
            int row = rh * 32 + rt * 16 + q * 4 + r;
            f4 v0 = *(const f4*)&s_red[row][0][0];
            f4 v1 = *(const f4*)&s_red[row][2][0];
            float t1 = v0[0] + v0[2] + v1[0] + v1[2];
            float t2 = v0[1] + v0[3] + v1[1] + v1[3];
            float mm = t1 * (1.f / 256.f);
            float vv = t2 * (1.f / 256.f) - mm * mm;
            m_[rt][r]  = mm;
            iv_[rt][r] = rsqrtf(vv + EPS);
        }
#pragma unroll
    for (int rt = 0; rt < 2; rt++)
#pragma unroll
        for (int c = 0; c < 4; c++) {
            int col = cs * 64 + c * 16 + lr;
#pragma unroll
            for (int r = 0; r < 4; r++)
                s_n[rh * 32 + rt * 16 + q * 4 + r][256 + col] =
                    cvt1((acc[rt][c][r] - m_[rt][r]) * iv_[rt][r]);
        }

    // ---------------- stage B: x_t = text @ text_w.T + text_b (K=768, direct loads) ----------------
#pragma unroll
    for (int rt = 0; rt < 2; rt++)
#pragma unroll
        for (int c = 0; c < 4; c++) acc[rt][c] = (f4){0.f, 0.f, 0.f, 0.f};

    const float* tp0 = text + (size_t)(R0 + rh * 32 + lr) * 768 + q * 8;
    const float* tp1 = tp0 + 16 * 768;
    const unsigned short* wb = twFL + (cs * 256 + lane) * 8;

#pragma unroll 4
    for (int ks = 0; ks < 24; ks++) {
        s8 bfr[4];
#pragma unroll
        for (int c = 0; c < 4; c++)
            bfr[c] = *(const s8*)&wb[(ks * 16 + c) * 512];
        f4 a0 = *(const f4*)(tp0 + ks * 32);
        f4 a1 = *(const f4*)(tp0 + ks * 32 + 4);
        f4 b0 = *(const f4*)(tp1 + ks * 32);
        f4 b1 = *(const f4*)(tp1 + ks * 32 + 4);
        s8 af0 = pack8(a0, a1);
        s8 af1 = pack8(b0, b1);
        __builtin_amdgcn_s_setprio(1);
#pragma unroll
        for (int c = 0; c < 4; c++)
            acc[0][c] = __builtin_amdgcn_mfma_f32_16x16x32_bf16(af0, bfr[c], acc[0][c], 0, 0, 0);
#pragma unroll
        for (int c = 0; c < 4; c++)
            acc[1][c] = __builtin_amdgcn_mfma_f32_16x16x32_bf16(af1, bfr[c], acc[1][c], 0, 0, 0);
        __builtin_amdgcn_s_setprio(0);
    }

    // bias + LN stats for text
#pragma unroll
    for (int rt = 0; rt < 2; rt++)
#pragma unroll
        for (int r = 0; r < 4; r++) { s1[rt][r] = 0.f; s2[rt][r] = 0.f; }
#pragma unroll
    for (int rt = 0; rt < 2; rt++)
#pragma unroll
        for (int c = 0; c < 4; c++) {
            float bb = text_b[cs * 64 + c * 16 + lr];
#pragma unroll
            for (int r = 0; r < 4; r++) {
                float x = acc[rt][c][r] + bb;
                acc[rt][c][r] = x;
                s1[rt][r] += x; s2[rt][r] += x * x;
            }
        }
#pragma unroll
    for (int off = 1; off < 16; off <<= 1)
#pragma unroll
        for (int rt = 0; rt < 2; rt++)
#pragma unroll
            for (int r = 0; r < 4; r++) {
                s1[rt][r] += __shfl_xor(s1[rt][r], off, 64);
                s2[rt][r] += __shfl_xor(s2[rt][r], off, 64);
            }
    __syncthreads();   // all waves' stage-A s_red reads complete
    if (lr == 0)
#pragma unroll
        for (int rt = 0; rt < 2; rt++)
#pragma unroll
            for (int r = 0; r < 4; r++) {
                int row = rh * 32 + rt * 16 + q * 4 + r;
                f2 v; v[0] = s1[rt][r]; v[1] = s2[rt][r];
                *(f2*)&s_red[row][cs][0] = v;
            }
    __syncthreads();
#pragma unroll
    for (int rt = 0; rt < 2; rt++)
#pragma unroll
        for (int r = 0; r < 4; r++) {
            int row = rh * 32 + rt * 16 + q * 4 + r;
            f4 v0 = *(const f4*)&s_red[row][0][0];
            f4 v1 = *(const f4*)&s_red[row][2][0];
            float t1 = v0[0] + v0[2] + v1[0] + v1[2];
            float t2 = v0[1] + v0[3] + v1[1] + v1[3];
            float mm = t1 * (1.f / 256.f);
            float vv = t2 * (1.f / 256.f) - mm * mm;
            m_[rt][r]  = mm;
            iv_[rt][r] = rsqrtf(vv + EPS);
        }
    // write n_t into cols 0..255
#pragma unroll
    for (int rt = 0; rt < 2; rt++)
#pragma unroll
        for (int c = 0; c < 4; c++) {
            int col = cs * 64 + c * 16 + lr;
#pragma unroll
            for (int r = 0; r < 4; r++)
                s_n[rh * 32 + rt * 16 + q * 4 + r][col] =
                    cvt1((acc[rt][c][r] - m_[rt][r]) * iv_[rt][r]);
        }
    __syncthreads();   // full s_n = [n_t | n_b] visible to all waves

    // ---------------- stage D: z = Wpq @ [n_t ; n_b] + dvec (K=512) ----------------
#pragma unroll
    for (int rt = 0; rt < 2; rt++)
#pragma unroll
        for (int c = 0; c < 4; c++) {
            float dv = dvec[cs * 64 + c * 16 + lr];
            acc[rt][c] = (f4){dv, dv, dv, dv};
        }
    const unsigned short* pb = pqFL + (cs * 256 + lane) * 8;
#pragma unroll 4
    for (int ks = 0; ks < 16; ks++) {
        s8 bfr[4];
#pragma unroll
        for (int c = 0; c < 4; c++)
            bfr[c] = *(const s8*)&pb[(ks * 16 + c) * 512];
        s8 af0 = *(const s8*)&s_n[rh * 32 + lr][ks * 32 + q * 8];
        s8 af1 = *(const s8*)&s_n[rh * 32 + 16 + lr][ks * 32 + q * 8];
        __builtin_amdgcn_s_setprio(1);
#pragma unroll
        for (int c = 0; c < 4; c++)
            acc[0][c] = __builtin_amdgcn_mfma_f32_16x16x32_bf16(af0, bfr[c], acc[0][c], 0, 0, 0);
#pragma unroll
        for (int c = 0; c < 4; c++)
            acc[1][c] = __builtin_amdgcn_mfma_f32_16x16x32_bf16(af1, bfr[c], acc[1][c], 0, 0, 0);
        __builtin_amdgcn_s_setprio(0);
    }

    // ---------------- epilogue: LN(z), relu, cls2 ----------------
#pragma unroll
    for (int rt = 0; rt < 2; rt++)
#pragma unroll
        for (int r = 0; r < 4; r++) { s1[rt][r] = 0.f; s2[rt][r] = 0.f; }
#pragma unroll
    for (int rt = 0; rt < 2; rt++)
#pragma unroll
        for (int c = 0; c < 4; c++)
#pragma unroll
            for (int r = 0; r < 4; r++) {
                float x = acc[rt][c][r];
                s1[rt][r] += x; s2[rt][r] += x * x;
            }
#pragma unroll
    for (int off = 1; off < 16; off <<= 1)
#pragma unroll
        for (int rt = 0; rt < 2; rt++)
#pragma unroll
            for (int r = 0; r < 4; r++) {
                s1[rt][r] += __shfl_xor(s1[rt][r], off, 64);
                s2[rt][r] += __shfl_xor(s2[rt][r], off, 64);
            }
    __syncthreads();   // stage-B s_red reads done
    if (lr == 0)
#pragma unroll
        for (int rt = 0; rt < 2; rt++)
#pragma unroll
            for (int r = 0; r < 4; r++) {
                int row = rh * 32 + rt * 16 + q * 4 + r;
                f2 v; v[0] = s1[rt][r]; v[1] = s2[rt][r];
                *(f2*)&s_red[row][cs][0] = v;
            }
    __syncthreads();
#pragma unroll
    for (int rt = 0; rt < 2; rt++)
#pragma unroll
        for (int r = 0; r < 4; r++) {
            int row = rh * 32 + rt * 16 + q * 4 + r;
            f4 v0 = *(const f4*)&s_red[row][0][0];
            f4 v1 = *(const f4*)&s_red[row][2][0];
            float t1 = v0[0] + v0[2] + v1[0] + v1[2];
            float t2 = v0[1] + v0[3] + v1[1] + v1[3];
            float mm = t1 * (1.f / 256.f);
            float vv = t2 * (1.f / 256.f) - mm * mm;
            m_[rt][r]  = mm;
            iv_[rt][r] = rsqrtf(vv + EPS);
        }
    float po0[2][4], po1[2][4];
#pragma unroll
    for (int rt = 0; rt < 2; rt++)
#pragma unroll
        for (int r = 0; r < 4; r++) { po0[rt][r] = 0.f; po1[rt][r] = 0.f; }
#pragma unroll
    for (int rt = 0; rt < 2; rt++)
#pragma unroll
        for (int c = 0; c < 4; c++) {
            int col = cs * 64 + c * 16 + lr;
            float gg = cls_ln_g[col], bb = cls_ln_b[col];
            float c0 = cls2_w[col],   c1 = cls2_w[256 + col];
#pragma unroll
            for (int r = 0; r < 4; r++) {
                float h = fmaxf((acc[rt][c][r] - m_[rt][r]) * iv_[rt][r] * gg + bb, 0.f);
                po0[rt][r] = fmaf(h, c0, po0[rt][r]);
                po1[rt][r] = fmaf(h, c1, po1[rt][r]);
            }
        }
#pragma unroll
    for (int off = 1; off < 16; off <<= 1)
#pragma unroll
        for (int rt = 0; rt < 2; rt++)
#pragma unroll
            for (int r = 0; r < 4; r++) {
                po0[rt][r] += __shfl_xor(po0[rt][r], off, 64);
                po1[rt][r] += __shfl_xor(po1[rt][r], off, 64);
            }
    __syncthreads();   // stats reads done; reuse s_red for po
    if (lr == 0)
#pragma unroll
        for (int rt = 0; rt < 2; rt++)
#pragma unroll
            for (int r = 0; r < 4; r++) {
                int row = rh * 32 + rt * 16 + q * 4 + r;
                f2 v; v[0] = po0[rt][r]; v[1] = po1[rt][r];
                *(f2*)&s_red[row][cs][0] = v;
            }
    __syncthreads();
    if (tid < 64) {
        int row = tid;
        f4 a = *(const f4*)&s_red[row][0][0];
        f4 b = *(const f4*)&s_red[row][2][0];
        f2 o;
        o[0] = a[0] + a[2] + b[0] + b[2] + cls2_b[0];
        o[1] = a[1] + a[3] + b[1] + b[3] + cls2_b[1];
        *(f2*)&out[(size_t)(R0 + row) * 2] = o;
    }
}

// ======================= launch =======================
extern "C" void kernel_launch(void* const* d_in, const int* in_sizes, int n_in,
                              void* d_out, int out_size, void* d_ws, size_t ws_size,
                              hipStream_t stream) {
    const float* bio       = (const float*)d_in[0];
    const float* text      = (const float*)d_in[1];
    const float* bio_w     = (const float*)d_in[2];
    const float* bio_b     = (const float*)d_in[3];
    const float* text_w    = (const float*)d_in[4];
    const float* text_b    = (const float*)d_in[5];
    const float* ln_bio_g  = (const float*)d_in[6];
    const float* ln_bio_b  = (const float*)d_in[7];
    const float* ln_text_g = (const float*)d_in[8];
    const float* ln_text_b = (const float*)d_in[9];
    const float* in_proj_w = (const float*)d_in[10];
    const float* in_proj_b = (const float*)d_in[11];
    const float* out_w     = (const float*)d_in[12];
    const float* out_b     = (const float*)d_in[13];
    const float* cls1_w    = (const float*)d_in[14];
    const float* cls1_b    = (const float*)d_in[15];
    const float* cls_ln_g  = (const float*)d_in[16];
    const float* cls_ln_b  = (const float*)d_in[17];
    const float* cls2_w    = (const float*)d_in[18];
    const float* cls2_b    = (const float*)d_in[19];
    float* out = (float*)d_out;

    float* ws   = (float*)d_ws;
    float* A    = ws;                 // 65536 fp32
    float* cvec = ws + 65536;         // 256
    float* dvec = ws + 65792;         // 256
    unsigned short* us   = (unsigned short*)(ws + 66048);
    unsigned short* twFL = us;            // 196608 bf16
    unsigned short* bwFL = us + 196608;   // 8192
    unsigned short* pqFL = us + 204800;   // 131072

    k_prep1  <<<356, 256, 0, stream>>>(text_w, bio_w, out_w, in_proj_w, in_proj_b, out_b,
                                       twFL, bwFL, A, cvec);
    k_prep_PQ<<<256, 256, 0, stream>>>(cls1_w, cls1_b, A, cvec,
                                       ln_text_g, ln_text_b, ln_bio_g, ln_bio_b,
                                       pqFL, dvec);

    int nrows = in_sizes[0] / 32;     // 65536
    k_main<<<nrows / 64, 512, 0, stream>>>(bio, text, bio_b, text_b,
                                           cls_ln_g, cls_ln_b, cls2_w, cls2_b,
                                           twFL, bwFL, pqFL, dvec, out);
}

// Round 2
// 381.037 us; speedup vs baseline: 1.1668x; 1.1668x over previous
//
#include <hip/hip_runtime.h>

typedef __attribute__((ext_vector_type(4))) float f4;
typedef __attribute__((ext_vector_type(2))) float f2;
typedef __attribute__((ext_vector_type(8))) short s8;   // 8 bf16 (4 VGPRs) MFMA frag

#define EPS 1e-5f

// ---- bit-exact RNE converters (prep kernels) ----
__device__ __forceinline__ unsigned short f2bf(float f) {
    union { float f; unsigned u; } v; v.f = f;
    unsigned u = v.u;
    return (unsigned short)((u + 0x7fffu + ((u >> 16) & 1u)) >> 16);   // RNE
}
__device__ __forceinline__ unsigned pack2(float a, float b) {
    return (unsigned)f2bf(a) | ((unsigned)f2bf(b) << 16);
}

// ---- single-instruction packed converters (main kernel) ----
__device__ __forceinline__ unsigned cvt_pk2(float a, float b) {
    unsigned r;
    asm("v_cvt_pk_bf16_f32 %0, %1, %2" : "=v"(r) : "v"(a), "v"(b));
    return r;
}
__device__ __forceinline__ unsigned short cvt1(float a) {
    return (unsigned short)cvt_pk2(a, a);
}
__device__ __forceinline__ s8 pack8(f4 a, f4 b) {
    union { s8 v; unsigned u[4]; } r;
    r.u[0] = cvt_pk2(a[0], a[1]); r.u[1] = cvt_pk2(a[2], a[3]);
    r.u[2] = cvt_pk2(b[0], b[1]); r.u[3] = cvt_pk2(b[2], b[3]);
    return r.v;
}

// ---- async global->LDS 16B (m97 pattern), with sync fallback ----
#if defined(__has_builtin)
#if __has_builtin(__builtin_amdgcn_global_load_lds)
#define HAVE_GLLDS 1
#endif
#endif
__device__ __forceinline__ void gl_lds16(const float* g, unsigned short* l) {
#ifdef HAVE_GLLDS
    __builtin_amdgcn_global_load_lds(
        (const __attribute__((address_space(1))) unsigned int*)g,
        (__attribute__((address_space(3))) unsigned int*)l, 16, 0, 0);
#else
    *(f4*)l = *(const f4*)g;
#endif
}

// =================== prep1 (merged): weight frag-linear bf16 + A/cvec ===================
// FL layout: FL[((ksg*16 + ct)*64 + lane)*8 + j] = W[ct*16 + (lane&15)][ksg*32 + (lane>>4)*8 + j]
__global__ __launch_bounds__(256) void k_prep1(const float* __restrict__ text_w,
                                               const float* __restrict__ bio_w,
                                               const float* __restrict__ out_w,
                                               const float* __restrict__ in_proj_w,
                                               const float* __restrict__ in_proj_b,
                                               const float* __restrict__ out_b,
                                               unsigned short* __restrict__ twFL,
                                               unsigned short* __restrict__ bwFL,
                                               float* __restrict__ A,
                                               float* __restrict__ cvec) {
    int b = blockIdx.x, t = threadIdx.x;
    if (b < 96) {                       // text_w [256][768] -> 24 ksteps x 16 ct
        int idx = b * 256 + t;
        int ksg = idx >> 10;
        int rem = idx & 1023;
        int ct = rem >> 6, lane = rem & 63;
        int n  = ct * 16 + (lane & 15);
        int k0 = ksg * 32 + ((lane >> 4) << 3);
        const float* src = &text_w[n * 768 + k0];
        f4 a = *(const f4*)src, c = *(const f4*)(src + 4);
        unsigned* dst = (unsigned*)&twFL[idx * 8];
        dst[0] = pack2(a[0], a[1]); dst[1] = pack2(a[2], a[3]);
        dst[2] = pack2(c[0], c[1]); dst[3] = pack2(c[2], c[3]);
    } else if (b < 100) {               // bio_w [256][32] -> 1 kstep x 16 ct
        int idx = (b - 96) * 256 + t;
        int ct = idx >> 6, lane = idx & 63;
        int n  = ct * 16 + (lane & 15);
        int k0 = (lane >> 4) << 3;
        const float* src = &bio_w[n * 32 + k0];
        f4 a = *(const f4*)src, c = *(const f4*)(src + 4);
        unsigned* dst = (unsigned*)&bwFL[idx * 8];
        dst[0] = pack2(a[0], a[1]); dst[1] = pack2(a[2], a[3]);
        dst[2] = pack2(c[0], c[1]); dst[3] = pack2(c[2], c[3]);
    } else {                            // A = out_w @ Wv, cvec = out_w @ bv + out_b
        __shared__ float srow[256];
        __shared__ float red[256];
        int i = b - 100, j = t;
        srow[j] = out_w[i * 256 + j];
        __syncthreads();
        float acc = 0.f;
#pragma unroll 16
        for (int k = 0; k < 256; k++)
            acc = fmaf(srow[k], in_proj_w[(512 + k) * 256 + j], acc);
        A[i * 256 + j] = acc;
        red[j] = srow[j] * in_proj_b[512 + j];
        __syncthreads();
        for (int s = 128; s > 0; s >>= 1) {
            if (j < s) red[j] += red[j + s];
            __syncthreads();
        }
        if (j == 0) cvec[i] = red[0] + out_b[i];
    }
}

// =================== prep2: PQ weights (frag-linear bf16, LN-gain folded) + dvec ===================
__global__ __launch_bounds__(256) void k_prep_PQ(const float* __restrict__ cls1_w,
                                                 const float* __restrict__ cls1_b,
                                                 const float* __restrict__ A,
                                                 const float* __restrict__ cvec,
                                                 const float* __restrict__ ln_text_g,
                                                 const float* __restrict__ ln_text_b,
                                                 const float* __restrict__ ln_bio_g,
                                                 const float* __restrict__ ln_bio_b,
                                                 unsigned short* __restrict__ pqFL,
                                                 float* __restrict__ dvec) {
    __shared__ float w1[256], w2[256], red[256];
    int i = blockIdx.x, j = threadIdx.x;
    w1[j] = cls1_w[i * 512 + j];
    w2[j] = cls1_w[i * 512 + 256 + j];
    __syncthreads();
    float rp = 0.f, rq = 0.f;
#pragma unroll 8
    for (int k = 0; k < 256; k++) {
        float a = A[k * 256 + j];
        rp = fmaf(w1[k], a, rp);
        rq = fmaf(w2[k], a, rq);
    }
    int ct   = i >> 4;
    int lane = (i & 15) | (((j >> 3) & 3) << 4);
    int jj   = j & 7;
    int ks1  = j >> 5;
    pqFL[(((ks1     ) * 16 + ct) * 64 + lane) * 8 + jj] = f2bf(rp * ln_text_g[j]);
    pqFL[(((ks1 + 8 ) * 16 + ct) * 64 + lane) * 8 + jj] = f2bf(rq * ln_bio_g[j]);
    red[j] = rp * ln_text_b[j] + rq * ln_bio_b[j] + (w1[j] + w2[j]) * cvec[j];
    __syncthreads();
    for (int s = 128; s > 0; s >>= 1) {
        if (j < s) red[j] += red[j + s];
        __syncthreads();
    }
    if (j == 0) dvec[i] = red[0] + cls1_b[i];
}

// =================== main fused MFMA kernel ===================
// 64 rows/block, 512 threads = 8 waves: wave = (cs = w&3 col-slice of 64, rh = w>>2 row-half of 32).
// ORDER: stage B (text GEMM, async LDS-staged f32 chunks overlaying s_n) -> LN_t -> n_t
//        stage A (bio GEMM, reg loads) -> LN_b -> n_b -> stage D (K=512) -> epilogue.
// Stage B: text staged via global_load_lds (f32, 96-col chunks, double-buffered, 1 barrier/chunk).
//   LDS layout: row-major [64][96] f32 (row stride 384B) with 16B-granule XOR swizzle
//   (byte ^= (row&7)<<4) applied on the READ side and inverse-applied to the GLOBAL source
//   address (global_load_lds dest must stay linear). Weights: depth-1 register prefetch.
__global__ __launch_bounds__(512, 4) void k_main(
    const float* __restrict__ bio, const float* __restrict__ text,
    const float* __restrict__ bio_b, const float* __restrict__ text_b,
    const float* __restrict__ cls_ln_g, const float* __restrict__ cls_ln_b,
    const float* __restrict__ cls2_w, const float* __restrict__ cls2_b,
    const unsigned short* __restrict__ twFL, const unsigned short* __restrict__ bwFL,
    const unsigned short* __restrict__ pqFL, const float* __restrict__ dvec,
    float* __restrict__ out)
{
    // s_n: [row][k] n_t 0..255 | n_b 256..511; row stride 520 u16 (2-way max on frag reads).
    // First 48KB double as the stage-B f32 staging buffers (dead before n_t/n_b written).
    __shared__ __align__(16) unsigned short s_n[64][520];  // 66560 B
    __shared__ __align__(16) float s_red[64][6][2];        // 3072 B; [row][cs][{a,b}]

    const int tid  = threadIdx.x;
    const int wv   = tid >> 6;
    const int cs   = wv & 3;          // col slice: cols [cs*64, cs*64+64)
    const int rh   = wv >> 2;         // row half: rows [rh*32, rh*32+32)
    const int lane = tid & 63;
    const int q    = lane >> 4;
    const int lr   = lane & 15;
    const int R0   = blockIdx.x * 64;

    unsigned short* sx = (unsigned short*)s_n;   // flat alias for staging
    const int SXU = 12288;                       // u16 per staging buffer (24KB)

    f4 acc[2][4];
    float s1[2][4], s2[2][4], m_[2][4], iv_[2][4];

    // ---- staging geometry: slot idx = i*512+tid; row=idx/24, j=idx%24 (16B slots) ----
    int sfofs[3], sdofs[3];
#pragma unroll
    for (int i = 0; i < 3; i++) {
        int idx = i * 512 + tid;
        int row = idx / 24;
        int j   = idx - row * 24;
        sfofs[i] = (R0 + row) * 768 + ((j ^ (row & 7)) << 2);  // inverse-swizzled source
        sdofs[i] = idx * 8;                                    // linear dest (u16)
    }
    // ---- stage-B LDS frag read offsets (swizzled), u16 units; add ks*64 per k-step ----
    int offB[2][2];
#pragma unroll
    for (int rt = 0; rt < 2; rt++) {
        int row = rh * 32 + rt * 16 + lr;
        int sw  = (row & 7) << 4;
        offB[rt][0] = (row * 384 + ((q * 32) ^ sw)) >> 1;
        offB[rt][1] = (row * 384 + (((q * 32) + 16) ^ sw)) >> 1;
    }

    // ---------------- prologue: stage chunk 0, prefetch weights kk=0 ----------------
#pragma unroll
    for (int i = 0; i < 3; i++)
        gl_lds16(text + sfofs[i], sx + sdofs[i]);

    const unsigned short* wb = twFL + (cs * 256 + lane) * 8;
    s8 wc[4], wn[4];
#pragma unroll
    for (int c = 0; c < 4; c++) wc[c] = *(const s8*)&wb[c * 512];
#pragma unroll
    for (int c = 0; c < 4; c++) wn[c] = wc[c];

#pragma unroll
    for (int rt = 0; rt < 2; rt++)
#pragma unroll
        for (int c = 0; c < 4; c++) acc[rt][c] = (f4){0.f, 0.f, 0.f, 0.f};

    __syncthreads();   // chunk 0 staged (vmcnt drained), wc arrived

    // ---------------- stage B: x_t = text @ text_w.T (K=768, 8 chunks x 3 ksteps) ----------------
    for (int ch = 0; ch < 8; ch++) {
        const int buf = ch & 1;
        if (ch < 7) {
            const float* src = text + (ch + 1) * 96;
            unsigned short* dst = sx + (buf ^ 1) * SXU;
#pragma unroll
            for (int i = 0; i < 3; i++)
                gl_lds16(src + sfofs[i], dst + sdofs[i]);
        }
        const unsigned short* sb = sx + buf * SXU;
#pragma unroll
        for (int ks = 0; ks < 3; ks++) {
            int kk = ch * 3 + ks;
            if (kk < 23) {
#pragma unroll
                for (int c = 0; c < 4; c++)
                    wn[c] = *(const s8*)&wb[((kk + 1) * 16 + c) * 512];
            }
            f4 lo0 = *(const f4*)&sb[offB[0][0] + ks * 64];
            f4 hi0 = *(const f4*)&sb[offB[0][1] + ks * 64];
            f4 lo1 = *(const f4*)&sb[offB[1][0] + ks * 64];
            f4 hi1 = *(const f4*)&sb[offB[1][1] + ks * 64];
            s8 af0 = pack8(lo0, hi0);
            s8 af1 = pack8(lo1, hi1);
#pragma unroll
            for (int c = 0; c < 4; c++)
                acc[0][c] = __builtin_amdgcn_mfma_f32_16x16x32_bf16(af0, wc[c], acc[0][c], 0, 0, 0);
#pragma unroll
            for (int c = 0; c < 4; c++)
                acc[1][c] = __builtin_amdgcn_mfma_f32_16x16x32_bf16(af1, wc[c], acc[1][c], 0, 0, 0);
#pragma unroll
            for (int c = 0; c < 4; c++) wc[c] = wn[c];
        }
        __syncthreads();   // staged chunk ready; all reads of buf done -> reusable
    }

    // ---- issue bio + bio-weight loads now (latency hides under LN_t) ----
    f4 bioA[2], bioB[2];
#pragma unroll
    for (int rt = 0; rt < 2; rt++) {
        const float* p = &bio[(size_t)(R0 + rh * 32 + rt * 16 + lr) * 32 + q * 8];
        bioA[rt] = *(const f4*)p;
        bioB[rt] = *(const f4*)(p + 4);
    }
    s8 bfrb[4];
#pragma unroll
    for (int c = 0; c < 4; c++)
        bfrb[c] = *(const s8*)&bwFL[((cs * 4 + c) * 64 + lane) * 8];

    // ---- LN_t: bias + stats + normalize -> n_t (cols 0..255) ----
#pragma unroll
    for (int rt = 0; rt < 2; rt++)
#pragma unroll
        for (int r = 0; r < 4; r++) { s1[rt][r] = 0.f; s2[rt][r] = 0.f; }
#pragma unroll
    for (int rt = 0; rt < 2; rt++)
#pragma unroll
        for (int c = 0; c < 4; c++) {
            float bb = text_b[cs * 64 + c * 16 + lr];
#pragma unroll
            for (int r = 0; r < 4; r++) {
                float x = acc[rt][c][r] + bb;
                acc[rt][c][r] = x;
                s1[rt][r] += x; s2[rt][r] += x * x;
            }
        }
#pragma unroll
    for (int off = 1; off < 16; off <<= 1)
#pragma unroll
        for (int rt = 0; rt < 2; rt++)
#pragma unroll
            for (int r = 0; r < 4; r++) {
                s1[rt][r] += __shfl_xor(s1[rt][r], off, 64);
                s2[rt][r] += __shfl_xor(s2[rt][r], off, 64);
            }
    if (lr == 0)
#pragma unroll
        for (int rt = 0; rt < 2; rt++)
#pragma unroll
            for (int r = 0; r < 4; r++) {
                int row = rh * 32 + rt * 16 + q * 4 + r;
                f2 v; v[0] = s1[rt][r]; v[1] = s2[rt][r];
                *(f2*)&s_red[row][cs][0] = v;
            }
    __syncthreads();
#pragma unroll
    for (int rt = 0; rt < 2; rt++)
#pragma unroll
        for (int r = 0; r < 4; r++) {
            int row = rh * 32 + rt * 16 + q * 4 + r;
            f4 v0 = *(const f4*)&s_red[row][0][0];
            f4 v1 = *(const f4*)&s_red[row][2][0];
            float t1 = v0[0] + v0[2] + v1[0] + v1[2];
            float t2 = v0[1] + v0[3] + v1[1] + v1[3];
            float mm = t1 * (1.f / 256.f);
            float vv = t2 * (1.f / 256.f) - mm * mm;
            m_[rt][r]  = mm;
            iv_[rt][r] = rsqrtf(vv + EPS);
        }
#pragma unroll
    for (int rt = 0; rt < 2; rt++)
#pragma unroll
        for (int c = 0; c < 4; c++) {
            int col = cs * 64 + c * 16 + lr;
#pragma unroll
            for (int r = 0; r < 4; r++)
                s_n[rh * 32 + rt * 16 + q * 4 + r][col] =
                    cvt1((acc[rt][c][r] - m_[rt][r]) * iv_[rt][r]);
        }

    // ---------------- stage A: x_b = bio @ bio_w.T + bio_b -> n_b (cols 256..511) ----------------
#pragma unroll
    for (int rt = 0; rt < 2; rt++)
#pragma unroll
        for (int c = 0; c < 4; c++) acc[rt][c] = (f4){0.f, 0.f, 0.f, 0.f};
#pragma unroll
    for (int rt = 0; rt < 2; rt++) {
        s8 af = pack8(bioA[rt], bioB[rt]);
#pragma unroll
        for (int c = 0; c < 4; c++)
            acc[rt][c] = __builtin_amdgcn_mfma_f32_16x16x32_bf16(af, bfrb[c], acc[rt][c], 0, 0, 0);
    }
#pragma unroll
    for (int rt = 0; rt < 2; rt++)
#pragma unroll
        for (int r = 0; r < 4; r++) { s1[rt][r] = 0.f; s2[rt][r] = 0.f; }
#pragma unroll
    for (int rt = 0; rt < 2; rt++)
#pragma unroll
        for (int c = 0; c < 4; c++) {
            float bb = bio_b[cs * 64 + c * 16 + lr];
#pragma unroll
            for (int r = 0; r < 4; r++) {
                float x = acc[rt][c][r] + bb;
                acc[rt][c][r] = x;
                s1[rt][r] += x; s2[rt][r] += x * x;
            }
        }
#pragma unroll
    for (int off = 1; off < 16; off <<= 1)
#pragma unroll
        for (int rt = 0; rt < 2; rt++)
#pragma unroll
            for (int r = 0; r < 4; r++) {
                s1[rt][r] += __shfl_xor(s1[rt][r], off, 64);
                s2[rt][r] += __shfl_xor(s2[rt][r], off, 64);
            }
    __syncthreads();   // LN_t s_red reads complete everywhere
    if (lr == 0)
#pragma unroll
        for (int rt = 0; rt < 2; rt++)
#pragma unroll
            for (int r = 0; r < 4; r++) {
                int row = rh * 32 + rt * 16 + q * 4 + r;
                f2 v; v[0] = s1[rt][r]; v[1] = s2[rt][r];
                *(f2*)&s_red[row][cs][0] = v;
            }
    __syncthreads();
#pragma unroll
    for (int rt = 0; rt < 2; rt++)
#pragma unroll
        for (int r = 0; r < 4; r++) {
            int row = rh * 32 + rt * 16 + q * 4 + r;
            f4 v0 = *(const f4*)&s_red[row][0][0];
            f4 v1 = *(const f4*)&s_red[row][2][0];
            float t1 = v0[0] + v0[2] + v1[0] + v1[2];
            float t2 = v0[1] + v0[3] + v1[1] + v1[3];
            float mm = t1 * (1.f / 256.f);
            float vv = t2 * (1.f / 256.f) - mm * mm;
            m_[rt][r]  = mm;
            iv_[rt][r] = rsqrtf(vv + EPS);
        }
#pragma unroll
    for (int rt = 0; rt < 2; rt++)
#pragma unroll
        for (int c = 0; c < 4; c++) {
            int col = cs * 64 + c * 16 + lr;
#pragma unroll
            for (int r = 0; r < 4; r++)
                s_n[rh * 32 + rt * 16 + q * 4 + r][256 + col] =
                    cvt1((acc[rt][c][r] - m_[rt][r]) * iv_[rt][r]);
        }
    __syncthreads();   // full s_n = [n_t | n_b] visible

    // ---------------- stage D: z = Wpq @ [n_t ; n_b] + dvec (K=512) ----------------
#pragma unroll
    for (int rt = 0; rt < 2; rt++)
#pragma unroll
        for (int c = 0; c < 4; c++) {
            float dv = dvec[cs * 64 + c * 16 + lr];
            acc[rt][c] = (f4){dv, dv, dv, dv};
        }
    const unsigned short* pb = pqFL + (cs * 256 + lane) * 8;
    s8 pc[4], pn[4];
#pragma unroll
    for (int c = 0; c < 4; c++) pc[c] = *(const s8*)&pb[c * 512];
#pragma unroll
    for (int c = 0; c < 4; c++) pn[c] = pc[c];
#pragma unroll
    for (int ks = 0; ks < 16; ks++) {
        if (ks < 15) {
#pragma unroll
            for (int c = 0; c < 4; c++)
                pn[c] = *(const s8*)&pb[((ks + 1) * 16 + c) * 512];
        }
        s8 af0 = *(const s8*)&s_n[rh * 32 + lr][ks * 32 + q * 8];
        s8 af1 = *(const s8*)&s_n[rh * 32 + 16 + lr][ks * 32 + q * 8];
#pragma unroll
        for (int c = 0; c < 4; c++)
            acc[0][c] = __builtin_amdgcn_mfma_f32_16x16x32_bf16(af0, pc[c], acc[0][c], 0, 0, 0);
#pragma unroll
        for (int c = 0; c < 4; c++)
            acc[1][c] = __builtin_amdgcn_mfma_f32_16x16x32_bf16(af1, pc[c], acc[1][c], 0, 0, 0);
#pragma unroll
        for (int c = 0; c < 4; c++) pc[c] = pn[c];
    }

    // ---------------- epilogue: LN(z), relu, cls2 ----------------
#pragma unroll
    for (int rt = 0; rt < 2; rt++)
#pragma unroll
        for (int r = 0; r < 4; r++) { s1[rt][r] = 0.f; s2[rt][r] = 0.f; }
#pragma unroll
    for (int rt = 0; rt < 2; rt++)
#pragma unroll
        for (int c = 0; c < 4; c++)
#pragma unroll
            for (int r = 0; r < 4; r++) {
                float x = acc[rt][c][r];
                s1[rt][r] += x; s2[rt][r] += x * x;
            }
#pragma unroll
    for (int off = 1; off < 16; off <<= 1)
#pragma unroll
        for (int rt = 0; rt < 2; rt++)
#pragma unroll
            for (int r = 0; r < 4; r++) {
                s1[rt][r] += __shfl_xor(s1[rt][r], off, 64);
                s2[rt][r] += __shfl_xor(s2[rt][r], off, 64);
            }
    if (lr == 0)
#pragma unroll
        for (int rt = 0; rt < 2; rt++)
#pragma unroll
            for (int r = 0; r < 4; r++) {
                int row = rh * 32 + rt * 16 + q * 4 + r;
                f2 v; v[0] = s1[rt][r]; v[1] = s2[rt][r];
                *(f2*)&s_red[row][cs][0] = v;
            }
    __syncthreads();
#pragma unroll
    for (int rt = 0; rt < 2; rt++)
#pragma unroll
        for (int r = 0; r < 4; r++) {
            int row = rh * 32 + rt * 16 + q * 4 + r;
            f4 v0 = *(const f4*)&s_red[row][0][0];
            f4 v1 = *(const f4*)&s_red[row][2][0];
            float t1 = v0[0] + v0[2] + v1[0] + v1[2];
            float t2 = v0[1] + v0[3] + v1[1] + v1[3];
            float mm = t1 * (1.f / 256.f);
            float vv = t2 * (1.f / 256.f) - mm * mm;
            m_[rt][r]  = mm;
            iv_[rt][r] = rsqrtf(vv + EPS);
        }
    float po0[2][4], po1[2][4];
#pragma unroll
    for (int rt = 0; rt < 2; rt++)
#pragma unroll
        for (int r = 0; r < 4; r++) { po0[rt][r] = 0.f; po1[rt][r] = 0.f; }
#pragma unroll
    for (int rt = 0; rt < 2; rt++)
#pragma unroll
        for (int c = 0; c < 4; c++) {
            int col = cs * 64 + c * 16 + lr;
            float gg = cls_ln_g[col], bb = cls_ln_b[col];
            float c0 = cls2_w[col],   c1 = cls2_w[256 + col];
#pragma unroll
            for (int r = 0; r < 4; r++) {
                float h = fmaxf((acc[rt][c][r] - m_[rt][r]) * iv_[rt][r] * gg + bb, 0.f);
                po0[rt][r] = fmaf(h, c0, po0[rt][r]);
                po1[rt][r] = fmaf(h, c1, po1[rt][r]);
            }
        }
#pragma unroll
    for (int off = 1; off < 16; off <<= 1)
#pragma unroll
        for (int rt = 0; rt < 2; rt++)
#pragma unroll
            for (int r = 0; r < 4; r++) {
                po0[rt][r] += __shfl_xor(po0[rt][r], off, 64);
                po1[rt][r] += __shfl_xor(po1[rt][r], off, 64);
            }
    __syncthreads();   // stats reads done; reuse s_red for po
    if (lr == 0)
#pragma unroll
        for (int rt = 0; rt < 2; rt++)
#pragma unroll
            for (int r = 0; r < 4; r++) {
                int row = rh * 32 + rt * 16 + q * 4 + r;
                f2 v; v[0] = po0[rt][r]; v[1] = po1[rt][r];
                *(f2*)&s_red[row][cs][0] = v;
            }
    __syncthreads();
    if (tid < 64) {
        int row = tid;
        f4 a = *(const f4*)&s_red[row][0][0];
        f4 b = *(const f4*)&s_red[row][2][0];
        f2 o;
        o[0] = a[0] + a[2] + b[0] + b[2] + cls2_b[0];
        o[1] = a[1] + a[3] + b[1] + b[3] + cls2_b[1];
        *(f2*)&out[(size_t)(R0 + row) * 2] = o;
    }
}

// ======================= launch =======================
extern "C" void kernel_launch(void* const* d_in, const int* in_sizes, int n_in,
                              void* d_out, int out_size, void* d_ws, size_t ws_size,
                              hipStream_t stream) {
    const float* bio       = (const float*)d_in[0];
    const float* text      = (const float*)d_in[1];
    const float* bio_w     = (const float*)d_in[2];
    const float* bio_b     = (const float*)d_in[3];
    const float* text_w    = (const float*)d_in[4];
    const float* text_b    = (const float*)d_in[5];
    const float* ln_bio_g  = (const float*)d_in[6];
    const float* ln_bio_b  = (const float*)d_in[7];
    const float* ln_text_g = (const float*)d_in[8];
    const float* ln_text_b = (const float*)d_in[9];
    const float* in_proj_w = (const float*)d_in[10];
    const float* in_proj_b = (const float*)d_in[11];
    const float* out_w     = (const float*)d_in[12];
    const float* out_b     = (const float*)d_in[13];
    const float* cls1_w    = (const float*)d_in[14];
    const float* cls1_b    = (const float*)d_in[15];
    const float* cls_ln_g  = (const float*)d_in[16];
    const float* cls_ln_b  = (const float*)d_in[17];
    const float* cls2_w    = (const float*)d_in[18];
    const float* cls2_b    = (const float*)d_in[19];
    float* out = (float*)d_out;

    float* ws   = (float*)d_ws;
    float* A    = ws;                 // 65536 fp32
    float* cvec = ws + 65536;         // 256
    float* dvec = ws + 65792;         // 256
    unsigned short* us   = (unsigned short*)(ws + 66048);
    unsigned short* twFL = us;            // 196608 bf16
    unsigned short* bwFL = us + 196608;   // 8192
    unsigned short* pqFL = us + 204800;   // 131072

    k_prep1  <<<356, 256, 0, stream>>>(text_w, bio_w, out_w, in_proj_w, in_proj_b, out_b,
                                       twFL, bwFL, A, cvec);
    k_prep_PQ<<<256, 256, 0, stream>>>(cls1_w, cls1_b, A, cvec,
                                       ln_text_g, ln_text_b, ln_bio_g, ln_bio_b,
                                       pqFL, dvec);

    int nrows = in_sizes[0] / 32;     // 65536
    k_main<<<nrows / 64, 512, 0, stream>>>(bio, text, bio_b, text_b,
                                           cls_ln_g, cls_ln_b, cls2_w, cls2_b,
                                           twFL, bwFL, pqFL, dvec, out);
}